// Round 7
// baseline (2253.937 us; speedup 1.0000x reference)
//
#include <hip/hip_runtime.h>
#include <math.h>

#define DEPTH 8
#define DIM   768
#define HID   1536
#define BATCH 64
#define NTOK  256
#define M_TOT (BATCH * NTOK)  // 16384

typedef unsigned short u16;
typedef unsigned int   u32;
typedef __bf16 bf16x8 __attribute__((ext_vector_type(8)));
typedef float  f32x4  __attribute__((ext_vector_type(4)));
typedef u16    u16x4  __attribute__((ext_vector_type(4)));

// round-to-nearest-even f32 -> bf16 (inputs are never NaN here)
__device__ __forceinline__ u16 f2bf(float f) {
    u32 u = __float_as_uint(f);
    u = (u + 0x7fff + ((u >> 16) & 1)) >> 16;
    return (u16)u;
}

__device__ __forceinline__ void stv(float* p, float v) { *p = v; }
__device__ __forceinline__ void stv(u16* p, float v)   { *p = f2bf(v); }

// async global->LDS, 16B per lane. LDS dest is wave-uniform base + lane*16;
// we pass the per-lane-consistent pointer (lane 0's value is the wave base).
__device__ __forceinline__ void gl2lds16(const void* g, void* l) {
#if __has_builtin(__builtin_amdgcn_global_load_lds)
    __builtin_amdgcn_global_load_lds(
        (__attribute__((address_space(1))) void*)(void*)g,
        (__attribute__((address_space(3))) void*)l, 16, 0, 0);
#else
    *(uint4*)l = *(const uint4*)g;  // fallback: per-lane copy (same layout)
#endif
}

// ---------------------------------------------------------------------------
// C[M,N] = A[M,K] * B[N,K]^T  (bf16 in, fp32 acc), m97-style structure.
// R5: XOR chunk swizzle on As/Bs (bank conflicts 1.4e7 -> 0).
// R6: XCD-aware 1D-grid swizzle (A-tile L2 residency; staging-BW bound fixed).
// MODE 0: out_f = acc + bias[col] + aux[(row&255)*N+col]   (patch embed)
// MODE 1: out_h = bf16(gelu_exact(acc + bias[col]))        (fc1 + GELU)
// MODE 2: out_f = aux[idx] + acc + bias[col]               (fc2 + residual)
// ---------------------------------------------------------------------------
template <int N, int K, int MODE>
__global__ __launch_bounds__(256) void gemm_bt(
    const u16* __restrict__ A, const u16* __restrict__ B,
    float* __restrict__ outf, u16* __restrict__ outh,
    const float* __restrict__ bias, const float* __restrict__ aux) {
    __shared__ __align__(16) u16 As[128 * 64];
    __shared__ __align__(16) u16 Bs[128 * 64];
    const int tid  = threadIdx.x;
    const int lane = tid & 63;
    const int lr   = lane & 15, quad = lane >> 4;
    const int wv   = tid >> 6;
    const int wrow = (wv >> 1) * 64, wcol = (wv & 1) * 64;
    // XCD-aware decode (grid = 1D, (M_TOT/128)*(N/128) blocks)
    constexpr int NN = N / 128;
    const int L    = blockIdx.x;
    const int xcd  = L & 7;
    const int slot = L >> 3;
    const int s    = slot / NN;
    const int nt   = slot - s * NN;
    const int tileM = (s * 8 + xcd) * 128, tileN = nt * 128;

    f32x4 acc[4][4];
#pragma unroll
    for (int i = 0; i < 4; ++i)
#pragma unroll
        for (int j = 0; j < 4; ++j) acc[i][j] = (f32x4){0.f, 0.f, 0.f, 0.f};

    for (int kt = 0; kt < K / 64; ++kt) {
        const int k0 = kt * 64;
#pragma unroll
        for (int it = 0; it < 4; ++it) {
            int linear = it * 256 + tid;
            int row = linear >> 3, kb = linear & 7;
            int kbs = kb ^ (row & 7);  // XOR-swizzled global source chunk
            gl2lds16(A + (size_t)(tileM + row) * K + (k0 + kbs * 8), &As[linear * 8]);
            gl2lds16(B + (size_t)(tileN + row) * K + (k0 + kbs * 8), &Bs[linear * 8]);
        }
        __syncthreads();
#pragma unroll
        for (int ks = 0; ks < 2; ++ks) {
            // global chunk (ks*4+quad) for row r lives at LDS chunk ^(r&7);
            // r&7 == lr&7 for all fragment rows (wrow/wcol/i*16 are mult of 16)
            const int sc = ((ks * 4 + quad) ^ (lr & 7)) * 8;
            bf16x8 af[4], bfr[4];
#pragma unroll
            for (int i = 0; i < 4; ++i)
                af[i] = *(const bf16x8*)&As[(wrow + i * 16 + lr) * 64 + sc];
#pragma unroll
            for (int j = 0; j < 4; ++j)
                bfr[j] = *(const bf16x8*)&Bs[(wcol + j * 16 + lr) * 64 + sc];
#pragma unroll
            for (int i = 0; i < 4; ++i)
#pragma unroll
                for (int j = 0; j < 4; ++j)
                    acc[i][j] = __builtin_amdgcn_mfma_f32_16x16x32_bf16(
                        af[i], bfr[j], acc[i][j], 0, 0, 0);
        }
        __syncthreads();
    }
    // epilogue: C/D layout col=lane&15, row=quad*4+r (verified m89)
#pragma unroll
    for (int i = 0; i < 4; ++i) {
#pragma unroll
        for (int j = 0; j < 4; ++j) {
            const int col = tileN + wcol + j * 16 + lr;
            const float bv = bias[col];
#pragma unroll
            for (int r = 0; r < 4; ++r) {
                const int row = tileM + wrow + i * 16 + quad * 4 + r;
                const size_t idx = (size_t)row * N + col;
                float v = acc[i][j][r] + bv;
                if (MODE == 0) {
                    outf[idx] = v + aux[(size_t)(row & 255) * N + col];
                } else if (MODE == 1) {
                    outh[idx] = f2bf(0.5f * v * (1.0f + erff(v * 0.70710678118654752f)));
                } else {
                    outf[idx] = aux[idx] + v;
                }
            }
        }
    }
}

// ---------------------------------------------------------------------------
// LayerNorm over last dim (768). One wave per row.
// ---------------------------------------------------------------------------
template <typename OutT>
__global__ __launch_bounds__(64) void k_ln(const float* __restrict__ in,
                                           OutT* __restrict__ out,
                                           const float* __restrict__ w,
                                           const float* __restrict__ bb) {
    const int row = blockIdx.x;
    const int lane = threadIdx.x;
    const float4* in4 = (const float4*)(in + (size_t)row * DIM);
    float4 v[3];
    float s = 0.f, s2 = 0.f;
#pragma unroll
    for (int j = 0; j < 3; ++j) {
        v[j] = in4[j * 64 + lane];
        s  += v[j].x + v[j].y + v[j].z + v[j].w;
        s2 += v[j].x * v[j].x + v[j].y * v[j].y + v[j].z * v[j].z + v[j].w * v[j].w;
    }
#pragma unroll
    for (int off = 32; off > 0; off >>= 1) {
        s  += __shfl_xor(s, off, 64);
        s2 += __shfl_xor(s2, off, 64);
    }
    const float m   = s * (1.0f / 768.0f);
    const float var = s2 * (1.0f / 768.0f) - m * m;
    const float rs  = rsqrtf(var + 1e-6f);
#pragma unroll
    for (int j = 0; j < 3; ++j) {
        const int kbase = (j * 64 + lane) * 4;
        float e[4] = {v[j].x, v[j].y, v[j].z, v[j].w};
#pragma unroll
        for (int q = 0; q < 4; ++q)
            stv(out + (size_t)row * DIM + kbase + q,
                (e[q] - m) * rs * w[kbase + q] + bb[kbase + q]);
    }
}

// LN stats only: per row mean + rsqrt(var+eps) -> stats[row] = {m, rs}
__global__ __launch_bounds__(64) void k_ln_stats(const float* __restrict__ in,
                                                 float2* __restrict__ stats) {
    const int row = blockIdx.x;
    const int lane = threadIdx.x;
    const float4* in4 = (const float4*)(in + (size_t)row * DIM);
    float s = 0.f, s2 = 0.f;
#pragma unroll
    for (int j = 0; j < 3; ++j) {
        float4 v = in4[j * 64 + lane];
        s  += v.x + v.y + v.z + v.w;
        s2 += v.x * v.x + v.y * v.y + v.z * v.z + v.w * v.w;
    }
#pragma unroll
    for (int off = 32; off > 0; off >>= 1) {
        s  += __shfl_xor(s, off, 64);
        s2 += __shfl_xor(s2, off, 64);
    }
    const float m   = s * (1.0f / 768.0f);
    const float var = s2 * (1.0f / 768.0f) - m * m;
    if (lane == 0) stats[row] = make_float2(m, rsqrtf(var + 1e-6f));
}

// fp32 -> bf16 bulk cast (float4 per thread)
__global__ void k_cast(const float* __restrict__ src, u16* __restrict__ dst, int n4) {
    int i = blockIdx.x * 256 + threadIdx.x;
    if (i >= n4) return;
    float4 f = ((const float4*)src)[i];
    ((u16x4*)dst)[i] = (u16x4){f2bf(f.x), f2bf(f.y), f2bf(f.z), f2bf(f.w)};
}

// x [64,3,256,256] -> A0 bf16 [16384, 768] (patch-major; k = c*256+p*16+q)
__global__ void k_repack(const float* __restrict__ x, u16* __restrict__ A0) {
    const int b = blockIdx.y;
    const int e = blockIdx.x * 256 + threadIdx.x;  // < 3*65536
    const int c = e >> 16;
    const int h = (e >> 8) & 255;
    const int w = e & 255;
    const int m = b * 256 + (h >> 4) * 16 + (w >> 4);
    const int k = c * 256 + (h & 15) * 16 + (w & 15);
    A0[(size_t)m * DIM + k] = f2bf(x[(size_t)b * 196608 + e]);
}

// Build real-space circular-conv kernels h[l][pix][d] from cw.
// h = ifft2(W_eff), W_eff = 0.5*(w_ext + conj(flip(w_ext))) — reproduces
// numpy irfftn's discard-imag semantics on the v=0 / v=8 bins exactly.
// Separable 2D DFT: stage A G(u,y)=sum_v W(u,v)e(vy); stage B Re sum_u G e(ux).
__global__ __launch_bounds__(256) void k_build_h(const float* __restrict__ cw,
                                                 float* __restrict__ h) {
    const int bi = blockIdx.x;
    const int l = bi / DIM, d = bi % DIM;
    __shared__ float raw[288];    // cw[l, u(16), v(9), d, ri(2)] slice
    __shared__ float wr[256], wi[256];
    __shared__ float gr[256], gi[256];
    __shared__ float cs[16], sn[16];
    const int tid = threadIdx.x;
    if (tid < 16) {
        float ang = 0.39269908169872414f * tid;  // 2*pi/16
        cs[tid] = cosf(ang);
        sn[tid] = sinf(ang);
    }
    for (int i = tid; i < 288; i += 256) {
        // i = (u*9+v)*2+ri
        raw[i] = cw[(((size_t)l * 144 + (size_t)(i >> 1)) * DIM + d) * 2 + (i & 1)];
    }
    __syncthreads();
    {   // Hermitian extension + symmetrization: W_eff(u,v) over full 16x16
        const int u = tid >> 4, v = tid & 15;
        float ar, ai, br, bi2;
        {   // w_ext(u, v)
            int uu = u, vv = v; float sg = 1.f;
            if (vv > 8) { uu = (16 - u) & 15; vv = 16 - v; sg = -1.f; }
            int idx = (uu * 9 + vv) * 2;
            ar = raw[idx]; ai = sg * raw[idx + 1];
        }
        {   // w_ext(-u, -v)
            int u2 = (16 - u) & 15, v2 = (16 - v) & 15;
            int uu = u2, vv = v2; float sg = 1.f;
            if (vv > 8) { uu = (16 - u2) & 15; vv = 16 - v2; sg = -1.f; }
            int idx = (uu * 9 + vv) * 2;
            br = raw[idx]; bi2 = sg * raw[idx + 1];
        }
        wr[tid] = 0.5f * (ar + br);
        wi[tid] = 0.5f * (ai - bi2);
    }
    __syncthreads();
    {   // stage A: tid = (u, y); G(u,y) = sum_v W(u,v) * e^{i 2pi v y/16}
        const int u = tid >> 4, y = tid & 15;
        float sr = 0.f, si = 0.f;
        int kk = 0;
#pragma unroll
        for (int v = 0; v < 16; ++v) {
            const float a = wr[u * 16 + v], b2 = wi[u * 16 + v];
            const float c = cs[kk], s = sn[kk];
            sr += a * c - b2 * s;
            si += a * s + b2 * c;
            kk = (kk + y) & 15;
        }
        gr[tid] = sr; gi[tid] = si;
    }
    __syncthreads();
    {   // stage B: tid = (x, y); h = (1/256) Re sum_u G(u,y) e^{i 2pi u x/16}
        const int x = tid >> 4, y = tid & 15;
        float acc = 0.f;
        int kk = 0;
#pragma unroll
        for (int u = 0; u < 16; ++u) {
            acc += gr[u * 16 + y] * cs[kk] - gi[u * 16 + y] * sn[kk];
            kk = (kk + x) & 15;
        }
        h[((size_t)l * 256 + x * 16 + y) * DIM + d] = acc * (1.0f / 256.0f);
    }
}

// Per-channel 16x16 circular conv. R7 retile: block = (16-ch group, batch PAIR).
// LDS 52KB (was 64KB) -> 3 blocks/CU resident (was 2); hs amortized over 2
// batches. Row stride padded to 17; thread's two output rows are xg and xg+8
// so in-wave xs rows are stride-1 (2 lanes/bank = free; stride-2 would be a
// 4-way conflict for ANY pad since 2*16*stride = 0 mod 32).
// LN1 affine fused into staging (stats + per-channel w,b in registers).
#define FCH 16
#define FST 17
__global__ __launch_bounds__(256) void k_filter(const float* __restrict__ tin,
                                                float* __restrict__ yout,
                                                const float2* __restrict__ stats,
                                                const float* __restrict__ lnw,
                                                const float* __restrict__ lnb,
                                                const float* __restrict__ hl) {
    const int g  = blockIdx.x;       // 0..47 (16-channel group)
    const int b0 = blockIdx.y * 2;   // batch pair
    __shared__ float ys[2][256 * FST];
    __shared__ float hs[256 * FST];
    const int tid = threadIdx.x;
    const int dl  = tid & 15;        // channel (same for staging & compute)
    const float wd = lnw[g * FCH + dl];
    const float bd = lnb[g * FCH + dl];
    const float* t0 = tin + (size_t)b0 * NTOK * DIM + g * FCH;
    const float* t1 = t0 + (size_t)NTOK * DIM;
    const float* hbase = hl + g * FCH;
    const float2* s0 = stats + b0 * NTOK;
    const float2* s1 = s0 + NTOK;
    {   // staging: 16 iters x (16 pix x 16 ch)
        const int pxs = tid >> 4;
        for (int it = 0; it < 16; ++it) {
            const int pix = it * 16 + pxs;
            hs[pix * FST + dl] = hbase[(size_t)pix * DIM + dl];
            const float2 a0 = s0[pix], a1 = s1[pix];
            ys[0][pix * FST + dl] = (t0[(size_t)pix * DIM + dl] - a0.x) * a0.y * wd + bd;
            ys[1][pix * FST + dl] = (t1[(size_t)pix * DIM + dl] - a1.x) * a1.y * wd + bd;
        }
    }
    __syncthreads();
    const int xg = (tid >> 4) & 7;   // output rows xg, xg+8
    const int bb = tid >> 7;         // which batch of the pair
    const float* ysb = ys[bb];
    float acc[2][16];
#pragma unroll
    for (int i = 0; i < 2; ++i)
#pragma unroll
        for (int j = 0; j < 16; ++j) acc[i][j] = 0.f;
    for (int a = 0; a < 16; ++a) {
        float hr[16];
#pragma unroll
        for (int c = 0; c < 16; ++c) hr[c] = hs[(a * 16 + c) * FST + dl];
#pragma unroll
        for (int xo = 0; xo < 2; ++xo) {
            const int xs = (xg + 8 * xo - a) & 15;
            float yr[16];
#pragma unroll
            for (int c = 0; c < 16; ++c) yr[c] = ysb[(xs * 16 + c) * FST + dl];
#pragma unroll
            for (int bt = 0; bt < 16; ++bt)
#pragma unroll
                for (int yy = 0; yy < 16; ++yy)
                    acc[xo][yy] = fmaf(hr[bt], yr[(yy - bt) & 15], acc[xo][yy]);
        }
    }
    float* obase = yout + (size_t)(b0 + bb) * NTOK * DIM + g * FCH;
#pragma unroll
    for (int xo = 0; xo < 2; ++xo) {
        const int xx = xg + 8 * xo;
#pragma unroll
        for (int yy = 0; yy < 16; ++yy)
            obase[(size_t)(xx * 16 + yy) * DIM + dl] = acc[xo][yy];
    }
}

// feat = mean over tokens of final-LN rows, then 2-way head dot. One block/batch.
__global__ __launch_bounds__(256) void k_final(const float* __restrict__ ln,
                                               const float* __restrict__ hw,
                                               const float* __restrict__ hb,
                                               float* __restrict__ out) {
    const int b = blockIdx.x, tid = threadIdx.x;
    __shared__ float feat[DIM];
    for (int d = tid; d < DIM; d += 256) {
        float s = 0.f;
        const float* p = ln + (size_t)b * NTOK * DIM + d;
        for (int n = 0; n < NTOK; ++n) s += p[(size_t)n * DIM];
        feat[d] = s * (1.0f / 256.0f);
    }
    __syncthreads();
    float p0 = 0.f, p1 = 0.f;
    for (int d = tid; d < DIM; d += 256) {
        float f = feat[d];
        p0 += f * hw[d];
        p1 += f * hw[DIM + d];
    }
#pragma unroll
    for (int off = 32; off > 0; off >>= 1) {
        p0 += __shfl_xor(p0, off, 64);
        p1 += __shfl_xor(p1, off, 64);
    }
    __shared__ float r0[4], r1[4];
    const int wv = tid >> 6, lane = tid & 63;
    if (lane == 0) { r0[wv] = p0; r1[wv] = p1; }
    __syncthreads();
    if (tid == 0) {
        out[b * 2 + 0] = r0[0] + r0[1] + r0[2] + r0[3] + hb[0];
        out[b * 2 + 1] = r1[0] + r1[1] + r1[2] + r1[3] + hb[1];
    }
}

extern "C" void kernel_launch(void* const* d_in, const int* in_sizes, int n_in,
                              void* d_out, int out_size, void* d_ws, size_t ws_size,
                              hipStream_t stream) {
    (void)in_sizes; (void)n_in; (void)out_size; (void)ws_size;
    const float* x      = (const float*)d_in[0];
    const float* conv_w = (const float*)d_in[1];
    const float* conv_b = (const float*)d_in[2];
    const float* pos    = (const float*)d_in[3];
    const float* cw     = (const float*)d_in[4];
    const float* ln1_w  = (const float*)d_in[5];
    const float* ln1_b  = (const float*)d_in[6];
    const float* ln2_w  = (const float*)d_in[7];
    const float* ln2_b  = (const float*)d_in[8];
    const float* fc1_w  = (const float*)d_in[9];
    const float* fc1_b  = (const float*)d_in[10];
    const float* fc2_w  = (const float*)d_in[11];
    const float* fc2_b  = (const float*)d_in[12];
    const float* norm_w = (const float*)d_in[13];
    const float* norm_b = (const float*)d_in[14];
    const float* head_w = (const float*)d_in[15];
    const float* head_b = (const float*)d_in[16];
    float* out = (float*)d_out;

    char* ws = (char*)d_ws;
    size_t off = 0;
    auto take = [&](size_t bytes) {
        char* p = ws + off;
        off += (bytes + 255) & ~(size_t)255;
        return p;
    };
    u16*   A0 = (u16*)take((size_t)M_TOT * DIM * 2);       // repacked patches, bf16
    u16*   Wc = (u16*)take((size_t)DIM * DIM * 2);         // conv_w bf16
    u16*   W1 = (u16*)take((size_t)DEPTH * HID * DIM * 2); // fc1 bf16
    u16*   W2 = (u16*)take((size_t)DEPTH * DIM * HID * 2); // fc2 bf16
    float* t  = (float*)take((size_t)M_TOT * DIM * 4);     // residual stream
    float* y1 = (float*)take((size_t)M_TOT * DIM * 4);     // filter out / final LN
    u16*   y2 = (u16*)take((size_t)M_TOT * DIM * 2);       // LN2 out, bf16
    u16*   gb = (u16*)take((size_t)M_TOT * HID * 2);       // GELU out, bf16
    float* hb = (float*)take((size_t)DEPTH * NTOK * DIM * 4);  // conv kernels
    float2* st = (float2*)take((size_t)M_TOT * 8);         // LN1 stats {m, rs}

    k_cast<<<(DIM * DIM / 4 + 255) / 256, 256, 0, stream>>>(conv_w, Wc, DIM * DIM / 4);
    k_cast<<<(DEPTH * HID * DIM / 4 + 255) / 256, 256, 0, stream>>>(fc1_w, W1, DEPTH * HID * DIM / 4);
    k_cast<<<(DEPTH * DIM * HID / 4 + 255) / 256, 256, 0, stream>>>(fc2_w, W2, DEPTH * DIM * HID / 4);
    k_repack<<<dim3(768, BATCH), 256, 0, stream>>>(x, A0);
    k_build_h<<<DEPTH * DIM, 256, 0, stream>>>(cw, hb);

    gemm_bt<DIM, DIM, 0><<<(M_TOT / 128) * (DIM / 128), 256, 0, stream>>>(
        A0, Wc, t, nullptr, conv_b, pos);

    for (int l = 0; l < DEPTH; ++l) {
        k_ln_stats<<<M_TOT, 64, 0, stream>>>(t, st);
        k_filter<<<dim3(DIM / FCH, BATCH / 2), 256, 0, stream>>>(
            t, y1, st, ln1_w + l * DIM, ln1_b + l * DIM, hb + (size_t)l * NTOK * DIM);
        k_ln<u16><<<M_TOT, 64, 0, stream>>>(y1, y2, ln2_w + l * DIM, ln2_b + l * DIM);
        gemm_bt<HID, DIM, 1><<<(M_TOT / 128) * (HID / 128), 256, 0, stream>>>(
            y2, W1 + (size_t)l * HID * DIM, nullptr, gb, fc1_b + l * HID, nullptr);
        gemm_bt<DIM, HID, 2><<<(M_TOT / 128) * (DIM / 128), 256, 0, stream>>>(
            gb, W2 + (size_t)l * DIM * HID, t, nullptr, fc2_b + l * DIM, t);
    }
    k_ln<float><<<M_TOT, 64, 0, stream>>>(t, y1, norm_w, norm_b);
    k_final<<<BATCH, 256, 0, stream>>>(y1, head_w, head_b, out);
}

// Round 8
// 2240.250 us; speedup vs baseline: 1.0061x; 1.0061x over previous
//
#include <hip/hip_runtime.h>
#include <math.h>

#define DEPTH 8
#define DIM   768
#define HID   1536
#define BATCH 64
#define NTOK  256
#define M_TOT (BATCH * NTOK)  // 16384

typedef unsigned short u16;
typedef unsigned int   u32;
typedef __bf16 bf16x8 __attribute__((ext_vector_type(8)));
typedef float  f32x4  __attribute__((ext_vector_type(4)));
typedef u16    u16x4  __attribute__((ext_vector_type(4)));

// round-to-nearest-even f32 -> bf16 (inputs are never NaN here)
__device__ __forceinline__ u16 f2bf(float f) {
    u32 u = __float_as_uint(f);
    u = (u + 0x7fff + ((u >> 16) & 1)) >> 16;
    return (u16)u;
}

__device__ __forceinline__ void stv(float* p, float v) { *p = v; }
__device__ __forceinline__ void stv(u16* p, float v)   { *p = f2bf(v); }

// async global->LDS, 16B per lane. LDS dest is wave-uniform base + lane*16;
// we pass the per-lane-consistent pointer (lane 0's value is the wave base).
__device__ __forceinline__ void gl2lds16(const void* g, void* l) {
#if __has_builtin(__builtin_amdgcn_global_load_lds)
    __builtin_amdgcn_global_load_lds(
        (__attribute__((address_space(1))) void*)(void*)g,
        (__attribute__((address_space(3))) void*)l, 16, 0, 0);
#else
    *(uint4*)l = *(const uint4*)g;  // fallback: per-lane copy (same layout)
#endif
}

// ---------------------------------------------------------------------------
// C[M,N] = A[M,K] * B[N,K]^T  (bf16 in, fp32 acc), m97-style structure.
// R5: XOR chunk swizzle on As/Bs (bank conflicts 1.4e7 -> 0).
// R6: XCD-aware 1D-grid swizzle (A-tile L2 residency; staging-BW bound fixed).
// MODE 0: out_f = acc + bias[col] + aux[(row&255)*N+col]   (patch embed)
// MODE 1: out_h = bf16(gelu_exact(acc + bias[col]))        (fc1 + GELU)
// MODE 2: out_f = aux[idx] + acc + bias[col]               (fc2 + residual)
// ---------------------------------------------------------------------------
template <int N, int K, int MODE>
__global__ __launch_bounds__(256) void gemm_bt(
    const u16* __restrict__ A, const u16* __restrict__ B,
    float* __restrict__ outf, u16* __restrict__ outh,
    const float* __restrict__ bias, const float* __restrict__ aux) {
    __shared__ __align__(16) u16 As[128 * 64];
    __shared__ __align__(16) u16 Bs[128 * 64];
    const int tid  = threadIdx.x;
    const int lane = tid & 63;
    const int lr   = lane & 15, quad = lane >> 4;
    const int wv   = tid >> 6;
    const int wrow = (wv >> 1) * 64, wcol = (wv & 1) * 64;
    // XCD-aware decode (grid = 1D, (M_TOT/128)*(N/128) blocks)
    constexpr int NN = N / 128;
    const int L    = blockIdx.x;
    const int xcd  = L & 7;
    const int slot = L >> 3;
    const int s    = slot / NN;
    const int nt   = slot - s * NN;
    const int tileM = (s * 8 + xcd) * 128, tileN = nt * 128;

    f32x4 acc[4][4];
#pragma unroll
    for (int i = 0; i < 4; ++i)
#pragma unroll
        for (int j = 0; j < 4; ++j) acc[i][j] = (f32x4){0.f, 0.f, 0.f, 0.f};

    for (int kt = 0; kt < K / 64; ++kt) {
        const int k0 = kt * 64;
#pragma unroll
        for (int it = 0; it < 4; ++it) {
            int linear = it * 256 + tid;
            int row = linear >> 3, kb = linear & 7;
            int kbs = kb ^ (row & 7);  // XOR-swizzled global source chunk
            gl2lds16(A + (size_t)(tileM + row) * K + (k0 + kbs * 8), &As[linear * 8]);
            gl2lds16(B + (size_t)(tileN + row) * K + (k0 + kbs * 8), &Bs[linear * 8]);
        }
        __syncthreads();
#pragma unroll
        for (int ks = 0; ks < 2; ++ks) {
            // global chunk (ks*4+quad) for row r lives at LDS chunk ^(r&7);
            // r&7 == lr&7 for all fragment rows (wrow/wcol/i*16 are mult of 16)
            const int sc = ((ks * 4 + quad) ^ (lr & 7)) * 8;
            bf16x8 af[4], bfr[4];
#pragma unroll
            for (int i = 0; i < 4; ++i)
                af[i] = *(const bf16x8*)&As[(wrow + i * 16 + lr) * 64 + sc];
#pragma unroll
            for (int j = 0; j < 4; ++j)
                bfr[j] = *(const bf16x8*)&Bs[(wcol + j * 16 + lr) * 64 + sc];
#pragma unroll
            for (int i = 0; i < 4; ++i)
#pragma unroll
                for (int j = 0; j < 4; ++j)
                    acc[i][j] = __builtin_amdgcn_mfma_f32_16x16x32_bf16(
                        af[i], bfr[j], acc[i][j], 0, 0, 0);
        }
        __syncthreads();
    }
    // epilogue: C/D layout col=lane&15, row=quad*4+r (verified m89)
#pragma unroll
    for (int i = 0; i < 4; ++i) {
#pragma unroll
        for (int j = 0; j < 4; ++j) {
            const int col = tileN + wcol + j * 16 + lr;
            const float bv = bias[col];
#pragma unroll
            for (int r = 0; r < 4; ++r) {
                const int row = tileM + wrow + i * 16 + quad * 4 + r;
                const size_t idx = (size_t)row * N + col;
                float v = acc[i][j][r] + bv;
                if (MODE == 0) {
                    outf[idx] = v + aux[(size_t)(row & 255) * N + col];
                } else if (MODE == 1) {
                    outh[idx] = f2bf(0.5f * v * (1.0f + erff(v * 0.70710678118654752f)));
                } else {
                    outf[idx] = aux[idx] + v;
                }
            }
        }
    }
}

// ---------------------------------------------------------------------------
// LayerNorm over last dim (768). One wave per row.
// ---------------------------------------------------------------------------
template <typename OutT>
__global__ __launch_bounds__(64) void k_ln(const float* __restrict__ in,
                                           OutT* __restrict__ out,
                                           const float* __restrict__ w,
                                           const float* __restrict__ bb) {
    const int row = blockIdx.x;
    const int lane = threadIdx.x;
    const float4* in4 = (const float4*)(in + (size_t)row * DIM);
    float4 v[3];
    float s = 0.f, s2 = 0.f;
#pragma unroll
    for (int j = 0; j < 3; ++j) {
        v[j] = in4[j * 64 + lane];
        s  += v[j].x + v[j].y + v[j].z + v[j].w;
        s2 += v[j].x * v[j].x + v[j].y * v[j].y + v[j].z * v[j].z + v[j].w * v[j].w;
    }
#pragma unroll
    for (int off = 32; off > 0; off >>= 1) {
        s  += __shfl_xor(s, off, 64);
        s2 += __shfl_xor(s2, off, 64);
    }
    const float m   = s * (1.0f / 768.0f);
    const float var = s2 * (1.0f / 768.0f) - m * m;
    const float rs  = rsqrtf(var + 1e-6f);
#pragma unroll
    for (int j = 0; j < 3; ++j) {
        const int kbase = (j * 64 + lane) * 4;
        float e[4] = {v[j].x, v[j].y, v[j].z, v[j].w};
#pragma unroll
        for (int q = 0; q < 4; ++q)
            stv(out + (size_t)row * DIM + kbase + q,
                (e[q] - m) * rs * w[kbase + q] + bb[kbase + q]);
    }
}

// LN stats only: per row mean + rsqrt(var+eps) -> stats[row] = {m, rs}
__global__ __launch_bounds__(64) void k_ln_stats(const float* __restrict__ in,
                                                 float2* __restrict__ stats) {
    const int row = blockIdx.x;
    const int lane = threadIdx.x;
    const float4* in4 = (const float4*)(in + (size_t)row * DIM);
    float s = 0.f, s2 = 0.f;
#pragma unroll
    for (int j = 0; j < 3; ++j) {
        float4 v = in4[j * 64 + lane];
        s  += v.x + v.y + v.z + v.w;
        s2 += v.x * v.x + v.y * v.y + v.z * v.z + v.w * v.w;
    }
#pragma unroll
    for (int off = 32; off > 0; off >>= 1) {
        s  += __shfl_xor(s, off, 64);
        s2 += __shfl_xor(s2, off, 64);
    }
    const float m   = s * (1.0f / 768.0f);
    const float var = s2 * (1.0f / 768.0f) - m * m;
    if (lane == 0) stats[row] = make_float2(m, rsqrtf(var + 1e-6f));
}

// fp32 -> bf16 bulk cast (float4 per thread)
__global__ void k_cast(const float* __restrict__ src, u16* __restrict__ dst, int n4) {
    int i = blockIdx.x * 256 + threadIdx.x;
    if (i >= n4) return;
    float4 f = ((const float4*)src)[i];
    ((u16x4*)dst)[i] = (u16x4){f2bf(f.x), f2bf(f.y), f2bf(f.z), f2bf(f.w)};
}

// x [64,3,256,256] -> A0 bf16 [16384, 768] (patch-major; k = c*256+p*16+q)
__global__ void k_repack(const float* __restrict__ x, u16* __restrict__ A0) {
    const int b = blockIdx.y;
    const int e = blockIdx.x * 256 + threadIdx.x;  // < 3*65536
    const int c = e >> 16;
    const int h = (e >> 8) & 255;
    const int w = e & 255;
    const int m = b * 256 + (h >> 4) * 16 + (w >> 4);
    const int k = c * 256 + (h & 15) * 16 + (w & 15);
    A0[(size_t)m * DIM + k] = f2bf(x[(size_t)b * 196608 + e]);
}

// Build real-space circular-conv kernels h[l][pix][d] from cw.
// h = ifft2(W_eff), W_eff = 0.5*(w_ext + conj(flip(w_ext))) — reproduces
// numpy irfftn's discard-imag semantics on the v=0 / v=8 bins exactly.
// Separable 2D DFT: stage A G(u,y)=sum_v W(u,v)e(vy); stage B Re sum_u G e(ux).
__global__ __launch_bounds__(256) void k_build_h(const float* __restrict__ cw,
                                                 float* __restrict__ h) {
    const int bi = blockIdx.x;
    const int l = bi / DIM, d = bi % DIM;
    __shared__ float raw[288];    // cw[l, u(16), v(9), d, ri(2)] slice
    __shared__ float wr[256], wi[256];
    __shared__ float gr[256], gi[256];
    __shared__ float cs[16], sn[16];
    const int tid = threadIdx.x;
    if (tid < 16) {
        float ang = 0.39269908169872414f * tid;  // 2*pi/16
        cs[tid] = cosf(ang);
        sn[tid] = sinf(ang);
    }
    for (int i = tid; i < 288; i += 256) {
        // i = (u*9+v)*2+ri
        raw[i] = cw[(((size_t)l * 144 + (size_t)(i >> 1)) * DIM + d) * 2 + (i & 1)];
    }
    __syncthreads();
    {   // Hermitian extension + symmetrization: W_eff(u,v) over full 16x16
        const int u = tid >> 4, v = tid & 15;
        float ar, ai, br, bi2;
        {   // w_ext(u, v)
            int uu = u, vv = v; float sg = 1.f;
            if (vv > 8) { uu = (16 - u) & 15; vv = 16 - v; sg = -1.f; }
            int idx = (uu * 9 + vv) * 2;
            ar = raw[idx]; ai = sg * raw[idx + 1];
        }
        {   // w_ext(-u, -v)
            int u2 = (16 - u) & 15, v2 = (16 - v) & 15;
            int uu = u2, vv = v2; float sg = 1.f;
            if (vv > 8) { uu = (16 - u2) & 15; vv = 16 - v2; sg = -1.f; }
            int idx = (uu * 9 + vv) * 2;
            br = raw[idx]; bi2 = sg * raw[idx + 1];
        }
        wr[tid] = 0.5f * (ar + br);
        wi[tid] = 0.5f * (ai - bi2);
    }
    __syncthreads();
    {   // stage A: tid = (u, y); G(u,y) = sum_v W(u,v) * e^{i 2pi v y/16}
        const int u = tid >> 4, y = tid & 15;
        float sr = 0.f, si = 0.f;
        int kk = 0;
#pragma unroll
        for (int v = 0; v < 16; ++v) {
            const float a = wr[u * 16 + v], b2 = wi[u * 16 + v];
            const float c = cs[kk], s = sn[kk];
            sr += a * c - b2 * s;
            si += a * s + b2 * c;
            kk = (kk + y) & 15;
        }
        gr[tid] = sr; gi[tid] = si;
    }
    __syncthreads();
    {   // stage B: tid = (x, y); h = (1/256) Re sum_u G(u,y) e^{i 2pi u x/16}
        const int x = tid >> 4, y = tid & 15;
        float acc = 0.f;
        int kk = 0;
#pragma unroll
        for (int u = 0; u < 16; ++u) {
            acc += gr[u * 16 + y] * cs[kk] - gi[u * 16 + y] * sn[kk];
            kk = (kk + x) & 15;
        }
        h[((size_t)l * 256 + x * 16 + y) * DIM + d] = acc * (1.0f / 256.0f);
    }
}

// Per-channel 16x16 circular conv. Block = (16-ch group, batch pair).
// R8: LDS layout transposed to [ch][pix] with row stride 260 floats
// (260*4B = 65*16B: 16B-aligned rows, 65%8=1 rotates bank-quads per channel).
// The c-loops (pixel-y) are now contiguous -> hr/yr gathers become
// ds_read_b128 (768 b32 -> 192 b128 per thread). R7 was dual-pipe
// issue-bound: FMA floor 41us, scalar-LDS 44us; b128 cuts LDS to ~23us.
// Staging writes (dl*4+pxs)%32 = 2 lanes/bank (free); b128 reads = 2
// address-distinct lanes per bank-quad (free, m136).
// LN1 affine fused into staging (stats + per-channel w,b in registers).
#define FCH 16
#define FPS 260   // padded pixel stride (floats)
__global__ __launch_bounds__(256) void k_filter(const float* __restrict__ tin,
                                                float* __restrict__ yout,
                                                const float2* __restrict__ stats,
                                                const float* __restrict__ lnw,
                                                const float* __restrict__ lnb,
                                                const float* __restrict__ hl) {
    const int g  = blockIdx.x;       // 0..47 (16-channel group)
    const int b0 = blockIdx.y * 2;   // batch pair
    __shared__ __align__(16) float ys[2][FCH * FPS];
    __shared__ __align__(16) float hs[FCH * FPS];
    const int tid = threadIdx.x;
    const int dl  = tid & 15;        // channel (same for staging & compute)
    const float wd = lnw[g * FCH + dl];
    const float bd = lnb[g * FCH + dl];
    const float* t0 = tin + (size_t)b0 * NTOK * DIM + g * FCH;
    const float* t1 = t0 + (size_t)NTOK * DIM;
    const float* hbase = hl + g * FCH;
    const float2* s0 = stats + b0 * NTOK;
    const float2* s1 = s0 + NTOK;
    {   // staging: 16 iters x (16 pix x 16 ch), transposed into [ch][pix]
        const int pxs = tid >> 4;
        for (int it = 0; it < 16; ++it) {
            const int pix = it * 16 + pxs;
            hs[dl * FPS + pix] = hbase[(size_t)pix * DIM + dl];
            const float2 a0 = s0[pix], a1 = s1[pix];
            ys[0][dl * FPS + pix] = (t0[(size_t)pix * DIM + dl] - a0.x) * a0.y * wd + bd;
            ys[1][dl * FPS + pix] = (t1[(size_t)pix * DIM + dl] - a1.x) * a1.y * wd + bd;
        }
    }
    __syncthreads();
    const int xg = (tid >> 4) & 7;   // output rows xg, xg+8
    const int bb = tid >> 7;         // which batch of the pair
    const float* ysb = ys[bb] + dl * FPS;
    const float* hsb = hs + dl * FPS;
    float acc[2][16];
#pragma unroll
    for (int i = 0; i < 2; ++i)
#pragma unroll
        for (int j = 0; j < 16; ++j) acc[i][j] = 0.f;
    for (int a = 0; a < 16; ++a) {
        float4 h4[4];
#pragma unroll
        for (int k = 0; k < 4; ++k) h4[k] = *(const float4*)&hsb[a * 16 + k * 4];
        const float hr[16] = {h4[0].x, h4[0].y, h4[0].z, h4[0].w,
                              h4[1].x, h4[1].y, h4[1].z, h4[1].w,
                              h4[2].x, h4[2].y, h4[2].z, h4[2].w,
                              h4[3].x, h4[3].y, h4[3].z, h4[3].w};
#pragma unroll
        for (int xo = 0; xo < 2; ++xo) {
            const int xs = (xg + 8 * xo - a) & 15;
            float4 y4[4];
#pragma unroll
            for (int k = 0; k < 4; ++k) y4[k] = *(const float4*)&ysb[xs * 16 + k * 4];
            const float yr[16] = {y4[0].x, y4[0].y, y4[0].z, y4[0].w,
                                  y4[1].x, y4[1].y, y4[1].z, y4[1].w,
                                  y4[2].x, y4[2].y, y4[2].z, y4[2].w,
                                  y4[3].x, y4[3].y, y4[3].z, y4[3].w};
#pragma unroll
            for (int bt = 0; bt < 16; ++bt)
#pragma unroll
                for (int yy = 0; yy < 16; ++yy)
                    acc[xo][yy] = fmaf(hr[bt], yr[(yy - bt) & 15], acc[xo][yy]);
        }
    }
    float* obase = yout + (size_t)(b0 + bb) * NTOK * DIM + g * FCH;
#pragma unroll
    for (int xo = 0; xo < 2; ++xo) {
        const int xx = xg + 8 * xo;
#pragma unroll
        for (int yy = 0; yy < 16; ++yy)
            obase[(size_t)(xx * 16 + yy) * DIM + dl] = acc[xo][yy];
    }
}

// feat = mean over tokens of final-LN rows, then 2-way head dot. One block/batch.
__global__ __launch_bounds__(256) void k_final(const float* __restrict__ ln,
                                               const float* __restrict__ hw,
                                               const float* __restrict__ hb,
                                               float* __restrict__ out) {
    const int b = blockIdx.x, tid = threadIdx.x;
    __shared__ float feat[DIM];
    for (int d = tid; d < DIM; d += 256) {
        float s = 0.f;
        const float* p = ln + (size_t)b * NTOK * DIM + d;
        for (int n = 0; n < NTOK; ++n) s += p[(size_t)n * DIM];
        feat[d] = s * (1.0f / 256.0f);
    }
    __syncthreads();
    float p0 = 0.f, p1 = 0.f;
    for (int d = tid; d < DIM; d += 256) {
        float f = feat[d];
        p0 += f * hw[d];
        p1 += f * hw[DIM + d];
    }
#pragma unroll
    for (int off = 32; off > 0; off >>= 1) {
        p0 += __shfl_xor(p0, off, 64);
        p1 += __shfl_xor(p1, off, 64);
    }
    __shared__ float r0[4], r1[4];
    const int wv = tid >> 6, lane = tid & 63;
    if (lane == 0) { r0[wv] = p0; r1[wv] = p1; }
    __syncthreads();
    if (tid == 0) {
        out[b * 2 + 0] = r0[0] + r0[1] + r0[2] + r0[3] + hb[0];
        out[b * 2 + 1] = r1[0] + r1[1] + r1[2] + r1[3] + hb[1];
    }
}

extern "C" void kernel_launch(void* const* d_in, const int* in_sizes, int n_in,
                              void* d_out, int out_size, void* d_ws, size_t ws_size,
                              hipStream_t stream) {
    (void)in_sizes; (void)n_in; (void)out_size; (void)ws_size;
    const float* x      = (const float*)d_in[0];
    const float* conv_w = (const float*)d_in[1];
    const float* conv_b = (const float*)d_in[2];
    const float* pos    = (const float*)d_in[3];
    const float* cw     = (const float*)d_in[4];
    const float* ln1_w  = (const float*)d_in[5];
    const float* ln1_b  = (const float*)d_in[6];
    const float* ln2_w  = (const float*)d_in[7];
    const float* ln2_b  = (const float*)d_in[8];
    const float* fc1_w  = (const float*)d_in[9];
    const float* fc1_b  = (const float*)d_in[10];
    const float* fc2_w  = (const float*)d_in[11];
    const float* fc2_b  = (const float*)d_in[12];
    const float* norm_w = (const float*)d_in[13];
    const float* norm_b = (const float*)d_in[14];
    const float* head_w = (const float*)d_in[15];
    const float* head_b = (const float*)d_in[16];
    float* out = (float*)d_out;

    char* ws = (char*)d_ws;
    size_t off = 0;
    auto take = [&](size_t bytes) {
        char* p = ws + off;
        off += (bytes + 255) & ~(size_t)255;
        return p;
    };
    u16*   A0 = (u16*)take((size_t)M_TOT * DIM * 2);       // repacked patches, bf16
    u16*   Wc = (u16*)take((size_t)DIM * DIM * 2);         // conv_w bf16
    u16*   W1 = (u16*)take((size_t)DEPTH * HID * DIM * 2); // fc1 bf16
    u16*   W2 = (u16*)take((size_t)DEPTH * DIM * HID * 2); // fc2 bf16
    float* t  = (float*)take((size_t)M_TOT * DIM * 4);     // residual stream
    float* y1 = (float*)take((size_t)M_TOT * DIM * 4);     // filter out / final LN
    u16*   y2 = (u16*)take((size_t)M_TOT * DIM * 2);       // LN2 out, bf16
    u16*   gb = (u16*)take((size_t)M_TOT * HID * 2);       // GELU out, bf16
    float* hb = (float*)take((size_t)DEPTH * NTOK * DIM * 4);  // conv kernels
    float2* st = (float2*)take((size_t)M_TOT * 8);         // LN1 stats {m, rs}

    k_cast<<<(DIM * DIM / 4 + 255) / 256, 256, 0, stream>>>(conv_w, Wc, DIM * DIM / 4);
    k_cast<<<(DEPTH * HID * DIM / 4 + 255) / 256, 256, 0, stream>>>(fc1_w, W1, DEPTH * HID * DIM / 4);
    k_cast<<<(DEPTH * DIM * HID / 4 + 255) / 256, 256, 0, stream>>>(fc2_w, W2, DEPTH * DIM * HID / 4);
    k_repack<<<dim3(768, BATCH), 256, 0, stream>>>(x, A0);
    k_build_h<<<DEPTH * DIM, 256, 0, stream>>>(cw, hb);

    gemm_bt<DIM, DIM, 0><<<(M_TOT / 128) * (DIM / 128), 256, 0, stream>>>(
        A0, Wc, t, nullptr, conv_b, pos);

    for (int l = 0; l < DEPTH; ++l) {
        k_ln_stats<<<M_TOT, 64, 0, stream>>>(t, st);
        k_filter<<<dim3(DIM / FCH, BATCH / 2), 256, 0, stream>>>(
            t, y1, st, ln1_w + l * DIM, ln1_b + l * DIM, hb + (size_t)l * NTOK * DIM);
        k_ln<u16><<<M_TOT, 64, 0, stream>>>(y1, y2, ln2_w + l * DIM, ln2_b + l * DIM);
        gemm_bt<HID, DIM, 1><<<(M_TOT / 128) * (HID / 128), 256, 0, stream>>>(
            y2, W1 + (size_t)l * HID * DIM, nullptr, gb, fc1_b + l * HID, nullptr);
        gemm_bt<DIM, HID, 2><<<(M_TOT / 128) * (DIM / 128), 256, 0, stream>>>(
            gb, W2 + (size_t)l * DIM * HID, t, nullptr, fc2_b + l * DIM, t);
    }
    k_ln<float><<<M_TOT, 64, 0, stream>>>(t, y1, norm_w, norm_b);
    k_final<<<BATCH, 256, 0, stream>>>(y1, head_w, head_b, out);
}